// Round 1
// baseline (775.299 us; speedup 1.0000x reference)
//
#include <hip/hip_runtime.h>

// 2-layer GCN on MI355X.
// Inputs: x[N,64] f32, edge_index[2,E] i32, W1[64,64], b1[64], W2[64,32], b2[32]
// Output: relu(Ahat @ relu(Ahat @ (x@W1) + b1) @ W2 + b2)  [N,32] f32
// Ahat = D^-1/2 (A + I) D^-1/2, deg over dst including self-loop.

__global__ __launch_bounds__(256) void k_init_deg(float* __restrict__ deg, int n) {
  int i = blockIdx.x * 256 + threadIdx.x;
  if (i < n) deg[i] = 1.0f;  // self-loop
}

__global__ __launch_bounds__(256) void k_accum_deg(const int* __restrict__ dst,
                                                   float* __restrict__ deg, int E) {
  int e = blockIdx.x * 256 + threadIdx.x;
  if (e < E) atomicAdd(&deg[dst[e]], 1.0f);
}

__global__ __launch_bounds__(256) void k_rsqrt(float* __restrict__ d, int n) {
  int i = blockIdx.x * 256 + threadIdx.x;
  if (i < n) d[i] = rsqrtf(d[i]);
}

// H[n,64] = X[n,64] @ W[64,64].  One wave per row; lane = out column.
__global__ __launch_bounds__(256) void k_gemm64(const float* __restrict__ X,
                                                const float* __restrict__ W,
                                                float* __restrict__ H, int n) {
  __shared__ float Wl[64 * 64];
  int tid = threadIdx.x;
#pragma unroll
  for (int i = 0; i < 16; ++i) Wl[i * 256 + tid] = W[i * 256 + tid];
  __syncthreads();
  int lane = tid & 63;
  int wv   = tid >> 6;           // 0..3
  int base = blockIdx.x * 64;    // 64 rows per block
  for (int it = 0; it < 16; ++it) {
    int row = base + it * 4 + wv;
    if (row >= n) return;        // monotone in it; no barriers below
    float xv = X[(size_t)row * 64 + lane];
    float acc = 0.f;
#pragma unroll
    for (int k = 0; k < 64; ++k)
      acc = fmaf(__shfl(xv, k), Wl[k * 64 + lane], acc);
    H[(size_t)row * 64 + lane] = acc;
  }
}

// H2[n,32] = relu(A[n,64] + b1) @ W2[64,32].  Half-wave (32 lanes) per row.
__global__ __launch_bounds__(256) void k_gemm32(const float* __restrict__ A,
                                                const float* __restrict__ b1,
                                                const float* __restrict__ W,
                                                float* __restrict__ H, int n) {
  __shared__ float Wl[64 * 32];
  int tid = threadIdx.x;
#pragma unroll
  for (int i = 0; i < 8; ++i) Wl[i * 256 + tid] = W[i * 256 + tid];
  __syncthreads();
  int col = tid & 31;
  int sub = (tid >> 5) & 1;      // which row of the wave's pair
  int wv  = tid >> 6;            // 0..3
  float b_lo = b1[col];
  float b_hi = b1[col + 32];
  int base = blockIdx.x * 64;    // 64 rows per block, 8 rows/iter
  for (int it = 0; it < 8; ++it) {
    int row = base + it * 8 + wv * 2 + sub;
    if (row >= n) return;        // monotone in it
    float a0 = fmaxf(A[(size_t)row * 64 + col]      + b_lo, 0.f);
    float a1 = fmaxf(A[(size_t)row * 64 + 32 + col] + b_hi, 0.f);
    float acc = 0.f;
#pragma unroll
    for (int k = 0; k < 32; ++k) {
      acc = fmaf(__shfl(a0, k, 32), Wl[k * 32 + col], acc);
      acc = fmaf(__shfl(a1, k, 32), Wl[(k + 32) * 32 + col], acc);
    }
    H[(size_t)row * 32 + col] = acc;
  }
}

// agg[i,f] = H[i,f] * dis[i]^2   (self-loop contribution; also zero-free init)
__global__ __launch_bounds__(256) void k_selfinit(const float* __restrict__ H,
                                                  const float* __restrict__ dis,
                                                  float* __restrict__ agg,
                                                  int n, int lg) {
  int idx = blockIdx.x * 256 + threadIdx.x;
  int total = n << lg;
  if (idx < total) {
    int i = idx >> lg;
    float dv = dis[i];
    agg[idx] = H[idx] * dv * dv;
  }
}

// One wave per edge, lane = feature (F=64).
__global__ __launch_bounds__(256) void k_scatter64(const int* __restrict__ src,
                                                   const int* __restrict__ dst,
                                                   const float* __restrict__ H,
                                                   const float* __restrict__ dis,
                                                   float* __restrict__ agg, int E) {
  int gid  = blockIdx.x * 256 + threadIdx.x;
  int e    = gid >> 6;
  int lane = gid & 63;
  if (e < E) {
    int s = src[e], d = dst[e];
    float nm = dis[s] * dis[d];
    atomicAdd(&agg[(size_t)d * 64 + lane], H[(size_t)s * 64 + lane] * nm);
  }
}

// Half-wave per edge (F=32).
__global__ __launch_bounds__(256) void k_scatter32(const int* __restrict__ src,
                                                   const int* __restrict__ dst,
                                                   const float* __restrict__ H,
                                                   const float* __restrict__ dis,
                                                   float* __restrict__ agg, int E) {
  int gid  = blockIdx.x * 256 + threadIdx.x;
  int e    = gid >> 5;
  int lane = gid & 31;
  if (e < E) {
    int s = src[e], d = dst[e];
    float nm = dis[s] * dis[d];
    atomicAdd(&agg[(size_t)d * 32 + lane], H[(size_t)s * 32 + lane] * nm);
  }
}

__global__ __launch_bounds__(256) void k_finish(const float* __restrict__ agg,
                                                const float* __restrict__ b2,
                                                float* __restrict__ out, int total) {
  int idx = blockIdx.x * 256 + threadIdx.x;
  if (idx < total) out[idx] = fmaxf(agg[idx] + b2[idx & 31], 0.f);
}

extern "C" void kernel_launch(void* const* d_in, const int* in_sizes, int n_in,
                              void* d_out, int out_size, void* d_ws, size_t ws_size,
                              hipStream_t stream) {
  const float* x  = (const float*)d_in[0];
  const int*   ei = (const int*)d_in[1];
  const float* W1 = (const float*)d_in[2];
  const float* b1 = (const float*)d_in[3];
  const float* W2 = (const float*)d_in[4];
  const float* b2 = (const float*)d_in[5];
  float* out = (float*)d_out;

  const int n = in_sizes[0] / 64;
  const int E = in_sizes[1] / 2;
  const int* src = ei;
  const int* dst = ei + E;

  // workspace layout (floats): dis[n] | h1[n*64] | agg1[n*64]
  // layer-2 h2/agg2 alias h1/agg1 (only n*32 each needed, prior data dead).
  float* dis  = (float*)d_ws;
  float* h1   = dis + n;
  float* agg1 = h1 + (size_t)n * 64;
  float* h2   = h1;
  float* agg2 = agg1;

  auto cdiv = [](long long a, long long b) { return (unsigned)((a + b - 1) / b); };
  dim3 B(256);

  k_init_deg <<<cdiv(n, 256),                 B, 0, stream>>>(dis, n);
  k_accum_deg<<<cdiv(E, 256),                 B, 0, stream>>>(dst, dis, E);
  k_rsqrt    <<<cdiv(n, 256),                 B, 0, stream>>>(dis, n);

  k_gemm64   <<<cdiv(n, 64),                  B, 0, stream>>>(x, W1, h1, n);
  k_selfinit <<<cdiv((long long)n * 64, 256), B, 0, stream>>>(h1, dis, agg1, n, 6);
  k_scatter64<<<cdiv((long long)E * 64, 256), B, 0, stream>>>(src, dst, h1, dis, agg1, E);

  k_gemm32   <<<cdiv(n, 64),                  B, 0, stream>>>(agg1, b1, W2, h2, n);
  k_selfinit <<<cdiv((long long)n * 32, 256), B, 0, stream>>>(h2, dis, agg2, n, 5);
  k_scatter32<<<cdiv((long long)E * 32, 256), B, 0, stream>>>(src, dst, h2, dis, agg2, E);

  k_finish   <<<cdiv((long long)n * 32, 256), B, 0, stream>>>(agg2, b2, out, n * 32);
}